// Round 11
// baseline (117.959 us; speedup 1.0000x reference)
//
#include <hip/hip_runtime.h>

// VNCMDLoss: SINGLE-kernel masked multi-reduction via native f32 atomics.
//  0 recon_real  (B,T)   f32      4 arrays x 8 MiB
//  1 recon_imag  (B,T)   f32
//  2 target_real (B,T)   f32
//  3 target_imag (B,T)   f32
//  4 eIF         (B,N,T) f32      64 MiB (masked rows skipped entirely)
//  5 target_if   (B,N,T) f32      64 MiB (masked rows skipped entirely)
//  6 mode_mask   (B,N)   i32
// Output: 4 x f32: total_loss, recon_loss, if_loss, smooth_loss
//
// Lessons encoded:
//  - R1->R2: FP64 atomicAdd = contended CAS loop (2x). (f32 atomicAdd is a
//    NATIVE fire-and-forget global_atomic_add_f32 -- different beast.)
//  - R3: __threadfence+ticket fusion => per-block L2 writeback on non-coherent
//    XCD L2s => 6x. No fences.
//  - R6: >8 loads in flight under VGPR cap => scratch spills. Batch = 8.
//  - R8: atomic ticket on the CRITICAL PATH (read-back before work) = 89us.
//    Here atomics are posted at block EXIT, no read-back, overlapped.
//  - R10: nt loads + lean finalize = 22.9us (best). This round removes the
//    finalize kernel entirely: the reduction is LINEAR in block partials and
//    count is derivable per-block from the 64-bit mask (one ballot), so each
//    block atomicAdds its 4 normalized contributions into out[0..3].
//    d_out zeroed each call by a graph-legal hipMemsetAsync node.

namespace {
constexpr int    kB = 8;
constexpr int    kN = 8;
constexpr int    kT = 262144;
constexpr long long kBT  = (long long)kB * kT;        // 2,097,152
constexpr long long kBNT = (long long)kB * kN * kT;   // 16,777,216

constexpr int THREADS  = 256;
constexpr int GRID     = 2048;      // 8 blocks/CU, full wave slots
constexpr int IF_SEGS  = 64;        // 1024 float4 per segment (8 loads/thread)

constexpr float LAMBDA_IF     = 0.5f;
constexpr float LAMBDA_SMOOTH = 0.1f;
}

typedef float vf4 __attribute__((ext_vector_type(4)));

__device__ __forceinline__ float sq(float x) { return x * x; }

// Non-temporal 16B load: read-once stream, skip cache allocation.
__device__ __forceinline__ vf4 ntld(const vf4* p) {
    return __builtin_nontemporal_load(p);
}

// recon unit u in [0,2048): one float4 per thread per array (4 nt loads).
__device__ __forceinline__ void recon_accum(int u, int tid,
                                            const vf4* __restrict__ rr4,
                                            const vf4* __restrict__ tr4,
                                            const vf4* __restrict__ ri4,
                                            const vf4* __restrict__ ti4,
                                            float& a0, float& a1) {
    const int v = u * THREADS + tid;          // [0, 524288)
    vf4 x = ntld(rr4 + v), y = ntld(tr4 + v);
    vf4 m = ntld(ri4 + v), w = ntld(ti4 + v);
    a0 += sq(x.x - y.x) + sq(x.y - y.y) + sq(x.z - y.z) + sq(x.w - y.w);
    a1 += sq(m.x - w.x) + sq(m.y - w.y) + sq(m.z - w.z) + sq(m.w - w.w);
}

// IF unit iu in [0,4096): (row, seg); masked rows contribute nothing.
__device__ __forceinline__ void if_accum(int iu, int tid,
                                         const float* __restrict__ eIF,
                                         const float* __restrict__ tIF,
                                         const int* __restrict__ mask,
                                         float& a2, float& a3) {
    const int row = iu >> 6;                  // block-uniform -> scalar load
    if (mask[row] != 1) return;
    const int seg = iu & (IF_SEGS - 1);

    const vf4* e4 = (const vf4*)(eIF + (size_t)row * kT);
    const vf4* t4 = (const vf4*)(tIF + (size_t)row * kT);
    constexpr int VPR = kT / 4;               // 65536 vectors per row
    const int base = seg * 1024 + tid;
    const int b0 = base, b1 = base + 256, b2 = base + 512, b3 = base + 768;
    const bool l63 = ((tid & 63) == 63);

    // 8 nt loads issued back-to-back (32 data VGPRs)
    vf4 e0 = ntld(e4 + b0), e1 = ntld(e4 + b1), e2 = ntld(e4 + b2), e3 = ntld(e4 + b3);
    vf4 q0 = ntld(t4 + b0), q1 = ntld(t4 + b1), q2 = ntld(t4 + b2), q3 = ntld(t4 + b3);
    float n0 = 0.f, n1 = 0.f, n2 = 0.f, n3 = 0.f;
    if (l63) {                                // wave-edge boundary scalars (cached)
        n0 = e4[b0 + 1].x;
        n1 = e4[b1 + 1].x;
        n2 = e4[b2 + 1].x;
        n3 = (b3 + 1 < VPR) ? e4[b3 + 1].x : e3.w;   // row end -> zero term
    }
    a2 += sq(e0.x - q0.x) + sq(e0.y - q0.y) + sq(e0.z - q0.z) + sq(e0.w - q0.w)
        + sq(e1.x - q1.x) + sq(e1.y - q1.y) + sq(e1.z - q1.z) + sq(e1.w - q1.w)
        + sq(e2.x - q2.x) + sq(e2.y - q2.y) + sq(e2.z - q2.z) + sq(e2.w - q2.w)
        + sq(e3.x - q3.x) + sq(e3.y - q3.y) + sq(e3.z - q3.z) + sq(e3.w - q3.w);
    a3 += sq(e0.y - e0.x) + sq(e0.z - e0.y) + sq(e0.w - e0.z)
        + sq(e1.y - e1.x) + sq(e1.z - e1.y) + sq(e1.w - e1.z)
        + sq(e2.y - e2.x) + sq(e2.z - e2.y) + sq(e2.w - e2.z)
        + sq(e3.y - e3.x) + sq(e3.z - e3.y) + sq(e3.w - e3.z);
    float s0 = __shfl_down(e0.x, 1, 64);
    float s1 = __shfl_down(e1.x, 1, 64);
    float s2 = __shfl_down(e2.x, 1, 64);
    float s3 = __shfl_down(e3.x, 1, 64);
    if (l63) { s0 = n0; s1 = n1; s2 = n2; s3 = n3; }
    a3 += sq(s0 - e0.w) + sq(s1 - e1.w) + sq(s2 - e2.w) + sq(s3 - e3.w);
}

__global__ __launch_bounds__(THREADS, 8)
void vncmd_main_kernel(const float* __restrict__ rr, const float* __restrict__ ri,
                       const float* __restrict__ tr, const float* __restrict__ ti,
                       const float* __restrict__ eIF, const float* __restrict__ tIF,
                       const int* __restrict__ mask, float* __restrict__ out) {
    const int tid  = threadIdx.x;
    const int bid  = blockIdx.x;
    const int lane = tid & 63;
    const int wid  = tid >> 6;

    // prologue: active-row count from the 64-bit mask (wave 0, one ballot)
    __shared__ int s_count;
    if (tid < 64) {
        const unsigned long long bits = __ballot(mask[tid] == 1);
        if (tid == 0) s_count = (int)__popcll(bits);
    }

    float a0 = 0.f, a1 = 0.f, a2 = 0.f, a3 = 0.f;
    recon_accum(bid, tid, (const vf4*)rr, (const vf4*)tr,
                (const vf4*)ri, (const vf4*)ti, a0, a1);
    if_accum(bid,        tid, eIF, tIF, mask, a2, a3);
    if_accum(bid + 2048, tid, eIF, tIF, mask, a2, a3);

    // ---- block reduction (fp32; block partials ~1e4, rel err ~1e-7) ----
    #pragma unroll
    for (int o = 32; o > 0; o >>= 1) {
        a0 += __shfl_down(a0, o, 64);
        a1 += __shfl_down(a1, o, 64);
        a2 += __shfl_down(a2, o, 64);
        a3 += __shfl_down(a3, o, 64);
    }
    __shared__ float lds[4][4];
    if (lane == 0) { lds[wid][0] = a0; lds[wid][1] = a1; lds[wid][2] = a2; lds[wid][3] = a3; }
    __syncthreads();                              // also publishes s_count
    if (tid == 0) {
        const float t0 = lds[0][0] + lds[1][0] + lds[2][0] + lds[3][0];
        const float t1 = lds[0][1] + lds[1][1] + lds[2][1] + lds[3][1];
        const float t2 = lds[0][2] + lds[1][2] + lds[2][2] + lds[3][2];
        const float t3 = lds[0][3] + lds[1][3] + lds[2][3] + lds[3][3];
        const float count = (float)s_count;
        // the final reduction is linear in block partials -> normalize here
        const float rc = (t0 + t1) * (1.0f / (float)kBT);            // recon contrib
        const float ic = t2 * (1.0f / (float)kBNT);                  // if contrib
        const float sc = t3 / ((float)(kT - 1) * fmaxf(count, 1.f)); // smooth contrib
        const float tc = rc + LAMBDA_IF * ic
                       + (count > 0.f ? LAMBDA_SMOOTH * sc : 0.f);   // total contrib
        // native f32 atomics, posted at block exit (not on critical path)
        atomicAdd(&out[0], tc);
        atomicAdd(&out[1], rc);
        atomicAdd(&out[2], ic);
        atomicAdd(&out[3], sc);
    }
}

extern "C" void kernel_launch(void* const* d_in, const int* in_sizes, int n_in,
                              void* d_out, int out_size, void* d_ws, size_t ws_size,
                              hipStream_t stream) {
    const float* rr  = (const float*)d_in[0];
    const float* ri  = (const float*)d_in[1];
    const float* tr  = (const float*)d_in[2];
    const float* ti  = (const float*)d_in[3];
    const float* eIF = (const float*)d_in[4];
    const float* tIF = (const float*)d_in[5];
    const int*   msk = (const int*)d_in[6];
    float* out = (float*)d_out;

    hipMemsetAsync(out, 0, 4 * sizeof(float), stream);  // graph-legal memset node
    vncmd_main_kernel<<<GRID, THREADS, 0, stream>>>(
        rr, ri, tr, ti, eIF, tIF, msk, out);
}

// Round 12
// 22.976 us; speedup vs baseline: 5.1341x; 5.1341x over previous
//
#include <hip/hip_runtime.h>

// VNCMDLoss: two-stage masked multi-reduction. R10 (measured best: 22.9us).
//  0 recon_real  (B,T)   f32      4 arrays x 8 MiB
//  1 recon_imag  (B,T)   f32
//  2 target_real (B,T)   f32
//  3 target_imag (B,T)   f32
//  4 eIF         (B,N,T) f32      64 MiB (masked rows skipped entirely)
//  5 target_if   (B,N,T) f32      64 MiB (masked rows skipped entirely)
//  6 mode_mask   (B,N)   i32
// Output: 4 x f32: total_loss, recon_loss, if_loss, smooth_loss
//
// Lessons encoded (final):
//  - ATOMICS: same-cacheline device-scope RMW serializes at ~10-15ns/op on
//    multi-XCD MI355X regardless of type: R1 FP64-CAS (53us), R8 uint ticket
//    (89us), R11 native f32 burst at block exit (112us -- waves can't retire
//    until vmcnt(0) drains the bounced line). >1k same-line atomics dominate
//    any kernel. Cross-block communication = plain stores to DISTINCT slots.
//  - R3: __threadfence+ticket fusion => per-block L2 writeback on
//    non-coherent XCD L2s => 6x. Kernel boundary IS the sync; never fence.
//  - R4: single-WAVE finalize = latency-serialized. Finalize >= 512 threads.
//  - R6: >8 loads in flight under VGPR cap => scratch spills. Batch = 8.
//  - R7 vs R9: mask load-imbalance is NOT the limiter (balanced units lost).
//  - R10: nt streaming loads + float4 partials + 512-thread finalize = best.
//    Main kernel ~17.5us = ~85% of achievable read BW on ~96MB touched;
//    + ~2.5us finalize + ~2us graph gaps = 22.9us total. Practical roofline.

namespace {
constexpr int    kB = 8;
constexpr int    kN = 8;
constexpr int    kT = 262144;
constexpr long long kBT  = (long long)kB * kT;        // 2,097,152
constexpr long long kBNT = (long long)kB * kN * kT;   // 16,777,216

constexpr int THREADS  = 256;
constexpr int GRID     = 2048;      // 8 blocks/CU, full wave slots
constexpr int IF_SEGS  = 64;        // 1024 float4 per segment (8 loads/thread)

constexpr double LAMBDA_IF     = 0.5;
constexpr double LAMBDA_SMOOTH = 0.1;
}

typedef float vf4 __attribute__((ext_vector_type(4)));

__device__ __forceinline__ float sq(float x) { return x * x; }

// Non-temporal 16B load: read-once stream, skip cache allocation.
__device__ __forceinline__ vf4 ntld(const vf4* p) {
    return __builtin_nontemporal_load(p);
}

// recon unit u in [0,2048): one float4 per thread per array (4 nt loads).
__device__ __forceinline__ void recon_accum(int u, int tid,
                                            const vf4* __restrict__ rr4,
                                            const vf4* __restrict__ tr4,
                                            const vf4* __restrict__ ri4,
                                            const vf4* __restrict__ ti4,
                                            float& a0, float& a1) {
    const int v = u * THREADS + tid;          // [0, 524288)
    vf4 x = ntld(rr4 + v), y = ntld(tr4 + v);
    vf4 m = ntld(ri4 + v), w = ntld(ti4 + v);
    a0 += sq(x.x - y.x) + sq(x.y - y.y) + sq(x.z - y.z) + sq(x.w - y.w);
    a1 += sq(m.x - w.x) + sq(m.y - w.y) + sq(m.z - w.z) + sq(m.w - w.w);
}

// IF unit iu in [0,4096): (row, seg); masked rows contribute nothing.
__device__ __forceinline__ void if_accum(int iu, int tid,
                                         const float* __restrict__ eIF,
                                         const float* __restrict__ tIF,
                                         const int* __restrict__ mask,
                                         float& a2, float& a3) {
    const int row = iu >> 6;                  // block-uniform -> scalar load
    if (mask[row] != 1) return;
    const int seg = iu & (IF_SEGS - 1);

    const vf4* e4 = (const vf4*)(eIF + (size_t)row * kT);
    const vf4* t4 = (const vf4*)(tIF + (size_t)row * kT);
    constexpr int VPR = kT / 4;               // 65536 vectors per row
    const int base = seg * 1024 + tid;
    const int b0 = base, b1 = base + 256, b2 = base + 512, b3 = base + 768;
    const bool l63 = ((tid & 63) == 63);

    // 8 nt loads issued back-to-back (32 data VGPRs)
    vf4 e0 = ntld(e4 + b0), e1 = ntld(e4 + b1), e2 = ntld(e4 + b2), e3 = ntld(e4 + b3);
    vf4 q0 = ntld(t4 + b0), q1 = ntld(t4 + b1), q2 = ntld(t4 + b2), q3 = ntld(t4 + b3);
    float n0 = 0.f, n1 = 0.f, n2 = 0.f, n3 = 0.f;
    if (l63) {                                // wave-edge boundary scalars (cached)
        n0 = e4[b0 + 1].x;
        n1 = e4[b1 + 1].x;
        n2 = e4[b2 + 1].x;
        n3 = (b3 + 1 < VPR) ? e4[b3 + 1].x : e3.w;   // row end -> zero term
    }
    a2 += sq(e0.x - q0.x) + sq(e0.y - q0.y) + sq(e0.z - q0.z) + sq(e0.w - q0.w)
        + sq(e1.x - q1.x) + sq(e1.y - q1.y) + sq(e1.z - q1.z) + sq(e1.w - q1.w)
        + sq(e2.x - q2.x) + sq(e2.y - q2.y) + sq(e2.z - q2.z) + sq(e2.w - q2.w)
        + sq(e3.x - q3.x) + sq(e3.y - q3.y) + sq(e3.z - q3.z) + sq(e3.w - q3.w);
    a3 += sq(e0.y - e0.x) + sq(e0.z - e0.y) + sq(e0.w - e0.z)
        + sq(e1.y - e1.x) + sq(e1.z - e1.y) + sq(e1.w - e1.z)
        + sq(e2.y - e2.x) + sq(e2.z - e2.y) + sq(e2.w - e2.z)
        + sq(e3.y - e3.x) + sq(e3.z - e3.y) + sq(e3.w - e3.z);
    float s0 = __shfl_down(e0.x, 1, 64);
    float s1 = __shfl_down(e1.x, 1, 64);
    float s2 = __shfl_down(e2.x, 1, 64);
    float s3 = __shfl_down(e3.x, 1, 64);
    if (l63) { s0 = n0; s1 = n1; s2 = n2; s3 = n3; }
    a3 += sq(s0 - e0.w) + sq(s1 - e1.w) + sq(s2 - e2.w) + sq(s3 - e3.w);
}

__global__ __launch_bounds__(THREADS, 8)
void vncmd_main_kernel(const float* __restrict__ rr, const float* __restrict__ ri,
                       const float* __restrict__ tr, const float* __restrict__ ti,
                       const float* __restrict__ eIF, const float* __restrict__ tIF,
                       const int* __restrict__ mask, float* __restrict__ ws) {
    const int tid  = threadIdx.x;
    const int bid  = blockIdx.x;
    const int lane = tid & 63;
    const int wid  = tid >> 6;

    float a0 = 0.f, a1 = 0.f, a2 = 0.f, a3 = 0.f;
    recon_accum(bid, tid, (const vf4*)rr, (const vf4*)tr,
                (const vf4*)ri, (const vf4*)ti, a0, a1);
    if_accum(bid,        tid, eIF, tIF, mask, a2, a3);
    if_accum(bid + 2048, tid, eIF, tIF, mask, a2, a3);

    // ---- single block reduction (fp32; partial ~1e5, rel err ~6e-8) ----
    #pragma unroll
    for (int o = 32; o > 0; o >>= 1) {
        a0 += __shfl_down(a0, o, 64);
        a1 += __shfl_down(a1, o, 64);
        a2 += __shfl_down(a2, o, 64);
        a3 += __shfl_down(a3, o, 64);
    }
    __shared__ float lds[4][4];
    if (lane == 0) { lds[wid][0] = a0; lds[wid][1] = a1; lds[wid][2] = a2; lds[wid][3] = a3; }
    __syncthreads();
    if (tid == 0) {
        vf4 r;
        r.x = lds[0][0] + lds[1][0] + lds[2][0] + lds[3][0];
        r.y = lds[0][1] + lds[1][1] + lds[2][1] + lds[3][1];
        r.z = lds[0][2] + lds[1][2] + lds[2][2] + lds[3][2];
        r.w = lds[0][3] + lds[1][3] + lds[2][3] + lds[3][3];
        ((vf4*)ws)[bid] = r;                  // distinct slot per block: no contention
    }
}

// 512-thread finalize: reduce 2048 float4 partials (32 KB) in double.
__global__ __launch_bounds__(512)
void finalize_kernel(const float* __restrict__ ws,
                     const int* __restrict__ mask,
                     float* __restrict__ out) {
    const int tid  = threadIdx.x;
    const int lane = tid & 63;
    const int wid  = tid >> 6;            // 8 waves

    const vf4* w4 = (const vf4*)ws;
    double s0 = 0.0, s1 = 0.0, s2 = 0.0, s3 = 0.0;
    #pragma unroll
    for (int k = 0; k < GRID / 512; ++k) {
        vf4 p = w4[k * 512 + tid];
        s0 += p.x; s1 += p.y; s2 += p.z; s3 += p.w;
    }
    #pragma unroll
    for (int o = 32; o > 0; o >>= 1) {
        s0 += __shfl_down(s0, o, 64);
        s1 += __shfl_down(s1, o, 64);
        s2 += __shfl_down(s2, o, 64);
        s3 += __shfl_down(s3, o, 64);
    }
    __shared__ double lds[8][4];
    if (lane == 0) { lds[wid][0] = s0; lds[wid][1] = s1; lds[wid][2] = s2; lds[wid][3] = s3; }
    __syncthreads();
    if (tid == 0) {
        double t0 = 0.0, t1 = 0.0, t2 = 0.0, t3 = 0.0;
        #pragma unroll
        for (int i = 0; i < 8; ++i) {
            t0 += lds[i][0]; t1 += lds[i][1]; t2 += lds[i][2]; t3 += lds[i][3];
        }
        int c = 0;
        #pragma unroll
        for (int i = 0; i < kB * kN; ++i) c += (mask[i] == 1);
        double count = (double)c;
        double recon = t0 / (double)kBT + t1 / (double)kBT;
        double ifl   = t2 / (double)kBNT;
        double denom = (count > 1.0 ? count : 1.0) * (double)(kT - 1);
        double smooth = t3 / denom;
        double total = recon + LAMBDA_IF * ifl + (count > 0.0 ? LAMBDA_SMOOTH * smooth : 0.0);
        out[0] = (float)total;
        out[1] = (float)recon;
        out[2] = (float)ifl;
        out[3] = (float)smooth;
    }
}

extern "C" void kernel_launch(void* const* d_in, const int* in_sizes, int n_in,
                              void* d_out, int out_size, void* d_ws, size_t ws_size,
                              hipStream_t stream) {
    const float* rr  = (const float*)d_in[0];
    const float* ri  = (const float*)d_in[1];
    const float* tr  = (const float*)d_in[2];
    const float* ti  = (const float*)d_in[3];
    const float* eIF = (const float*)d_in[4];
    const float* tIF = (const float*)d_in[5];
    const int*   msk = (const int*)d_in[6];
    float* out = (float*)d_out;
    float* ws  = (float*)d_ws;

    vncmd_main_kernel<<<GRID, THREADS, 0, stream>>>(
        rr, ri, tr, ti, eIF, tIF, msk, ws);
    finalize_kernel<<<1, 512, 0, stream>>>(ws, msk, out);
}